// Round 4
// baseline (328.005 us; speedup 1.0000x reference)
//
#include <hip/hip_runtime.h>
#include <hip/hip_bf16.h>

typedef __attribute__((ext_vector_type(2))) float          f32x2;
typedef __attribute__((ext_vector_type(4))) float          f32x4;
typedef __attribute__((ext_vector_type(8))) short          bf16x8;
typedef __attribute__((ext_vector_type(8))) unsigned short ushort8;

#define NB_ 16
#define NF_ 256
#define E_  2048
#define T_  4096
#define BM_ 256
#define BN_ 256
#define BK_ 32
#define NKT (E_ / BK_)   // 64 K-steps

__device__ __forceinline__ unsigned short f2bf(float x) {
    __hip_bfloat16 h = __float2bfloat16(x);
    return __builtin_bit_cast(unsigned short, h);
}

__device__ __forceinline__ void gload_lds16(const float* g, float* l) {
    __builtin_amdgcn_global_load_lds(
        (const __attribute__((address_space(1))) void*)g,
        (__attribute__((address_space(3))) void*)l, 16, 0, 0);
}

__global__ __launch_bounds__(1024, 4)
void mesh_unpool_gemm(const float* __restrict__ features,
                      const float* __restrict__ groups,
                      const float* __restrict__ occur,
                      float* __restrict__ out)
{
    extern __shared__ char smem[];
    float* As0 = (float*)smem;                 // 3 x 32 KB fp32 A tiles (linear, src-swizzled)
    float* As1 = As0 + BM_ * BK_;
    float* As2 = As1 + BM_ * BK_;
    unsigned short* Bs0 = (unsigned short*)(As2 + BM_ * BK_);   // 2 x 16 KB bf16 B tiles
    unsigned short* Bs1 = Bs0 + BN_ * BK_;

    // 256 blocks, 1/CU. xcd = bid&7 (round-robin dispatch); 2 batches per XCD.
    const int bid = blockIdx.x;
    const int xcd = bid & 7;
    const int s   = bid >> 3;             // 0..31
    const int b   = xcd * 2 + (s >> 4);   // batch
    const int n0  = (s & 15) * BN_;       // t-column block

    const float* __restrict__ fA = features + (size_t)b * NF_ * E_;
    const float* __restrict__ fB = groups   + (size_t)b * E_ * T_;
    const float* __restrict__ fO = occur    + (size_t)b * T_;
    float* __restrict__ fC       = out      + (size_t)b * NF_ * T_;

    const int tid  = threadIdx.x;
    const int lane = tid & 63;
    const int wave = tid >> 6;            // 0..15
    const int wm   = wave >> 2;           // 0..3 (M quadrant)
    const int wn   = wave & 3;            // 0..3 (N quadrant)
    const int l15  = lane & 15;
    const int kg   = lane >> 4;           // frag k-offset = kg*8
    const int sw   = (l15 >> 2) & 3;
    const int bko  = (kg ^ sw) << 3;      // B chunk elem offset (shorts)
    const int r7   = l15 & 7;
    const int ac0  = (((2 * kg)     ^ r7) << 2);   // A phys chunk float offsets
    const int ac1  = (((2 * kg + 1) ^ r7) << 2);

    // A staging (global_load_lds): instr j of wave w covers rows w*16+j*8+(lane>>3);
    // source chunk pre-swizzled (lane&7)^(row&7), LDS dest linear.
    const int srow = lane >> 3;
    const int schk = (lane & 7) ^ srow;
    const float* aSrc = fA + (size_t)(wave * 16 + srow) * E_ + schk * 4;

    // B staging: thread (kq = tid>>7, cp = tid&127) covers k-quad 4kq..4kq+3,
    // cols 2cp, 2cp+1. Loads f32x2 coalesced; stores 2 x ds_write_b64.
    const int kq = tid >> 7;              // 0..7
    const int cp = tid & 127;             // 0..127
    const float* bSrc = fB + (size_t)(4 * kq) * T_ + n0 + 2 * cp;

    f32x2 br0[4], br1[4];                 // depth-2 B register buffers
    f32x4 acc[4][4];
    #pragma unroll
    for (int i = 0; i < 4; ++i)
        #pragma unroll
        for (int j = 0; j < 4; ++j)
            acc[i][j] = (f32x4){0.f, 0.f, 0.f, 0.f};

    auto issueA = [&](float* AsT, int kt) {
        const float* src = aSrc + kt * BK_;
        #pragma unroll
        for (int j = 0; j < 2; ++j)
            gload_lds16(src + (size_t)j * 8 * E_, &AsT[(wave * 16 + j * 8) * BK_]);
    };
    auto loadB = [&](f32x2 (&br)[4], int kt) {
        const float* src = bSrc + (size_t)kt * BK_ * T_;
        #pragma unroll
        for (int j = 0; j < 4; ++j)
            br[j] = *(const f32x2*)(src + (size_t)j * T_);
    };
    auto storeB = [&](unsigned short* BsT, f32x2 (&br)[4]) {
        #pragma unroll
        for (int ii = 0; ii < 2; ++ii) {
            const int i = (ii + cp) & 1;         // rotation: spreads t&1 across lanes
            const int t = 2 * cp + i;
            unsigned p0 = (unsigned)f2bf(br[0][i]) | ((unsigned)f2bf(br[1][i]) << 16);
            unsigned p1 = (unsigned)f2bf(br[2][i]) | ((unsigned)f2bf(br[3][i]) << 16);
            const int off = t * BK_ + (((kq >> 1) ^ ((t >> 2) & 3)) << 3) + ((kq & 1) << 2);
            *(uint2*)&BsT[off] = make_uint2(p0, p1);
        }
    };
    auto compute = [&](const float* AsT, const unsigned short* BsT) {
        bf16x8 bfr[4];
        #pragma unroll
        for (int fn = 0; fn < 4; ++fn)
            bfr[fn] = *(const bf16x8*)&BsT[(wn * 64 + fn * 16 + l15) * BK_ + bko];
        #pragma unroll
        for (int fm = 0; fm < 4; ++fm) {
            const float* ar = &AsT[(wm * 64 + fm * 16 + l15) * BK_];
            f32x4 a0 = *(const f32x4*)(ar + ac0);
            f32x4 a1 = *(const f32x4*)(ar + ac1);
            ushort8 ap;
            #pragma unroll
            for (int e = 0; e < 4; ++e) { ap[e] = f2bf(a0[e]); ap[4 + e] = f2bf(a1[e]); }
            bf16x8 af = __builtin_bit_cast(bf16x8, ap);
            #pragma unroll
            for (int fn = 0; fn < 4; ++fn)
                acc[fm][fn] = __builtin_amdgcn_mfma_f32_16x16x32_bf16(
                    af, bfr[fn], acc[fm][fn], 0, 0, 0);
        }
    };

    // Steady step kt: loadB(kt+2), issueA(kt+2), vmcnt(8)->storeB(kt+1),
    // compute(kt), vmcnt(6) [drains A(kt+1)], lgkm(0), barrier.
    // 6 loads (B(kt+2)x4 + A(kt+2)x2) stay in flight across every barrier.
#define STEP_FULL(KT, AC, AN, BC, BNS, BLD, BST)                        \
    {                                                                   \
        loadB(BLD, (KT) + 2);                                           \
        issueA(AN, (KT) + 2);                                           \
        __builtin_amdgcn_sched_barrier(0);                              \
        asm volatile("s_waitcnt vmcnt(8)" ::: "memory");                \
        storeB(BNS, BST);                                               \
        compute(AC, BC);                                                \
        __builtin_amdgcn_sched_barrier(0);                              \
        asm volatile("s_waitcnt vmcnt(6)" ::: "memory");                \
        asm volatile("s_waitcnt lgkmcnt(0)" ::: "memory");              \
        __builtin_amdgcn_s_barrier();                                   \
    }

    // Prologue: B(0),A(0),B(1),A(1) issued; drain B(0) -> store; drain A(0); barrier.
    loadB(br0, 0);
    issueA(As0, 0);
    loadB(br1, 1);
    issueA(As1, 1);
    __builtin_amdgcn_sched_barrier(0);
    asm volatile("s_waitcnt vmcnt(8)" ::: "memory");   // B(0) done
    storeB(Bs0, br0);
    __builtin_amdgcn_sched_barrier(0);
    asm volatile("s_waitcnt vmcnt(6)" ::: "memory");   // A(0) done; B(1)+A(1) in flight
    asm volatile("s_waitcnt lgkmcnt(0)" ::: "memory");
    __builtin_amdgcn_s_barrier();

    // Steady: kt = 0..59 (period-6 static buffer rotation), then tail 60..63.
    for (int p = 0; p < 10; ++p) {
        const int kt = p * 6;
        STEP_FULL(kt + 0, As0, As2, Bs0, Bs1, br0, br1);
        STEP_FULL(kt + 1, As1, As0, Bs1, Bs0, br1, br0);
        STEP_FULL(kt + 2, As2, As1, Bs0, Bs1, br0, br1);
        STEP_FULL(kt + 3, As0, As2, Bs1, Bs0, br1, br0);
        STEP_FULL(kt + 4, As1, As0, Bs0, Bs1, br0, br1);
        STEP_FULL(kt + 5, As2, As1, Bs1, Bs0, br1, br0);
    }
    STEP_FULL(60, As0, As2, Bs0, Bs1, br0, br1);
    STEP_FULL(61, As1, As0, Bs1, Bs0, br1, br0);
    // kt = 62: nothing left to issue; store B(63); full drain at end.
    {
        asm volatile("s_waitcnt vmcnt(2)" ::: "memory");   // B(63) done
        storeB(Bs1, br1);
        compute(As2, Bs0);
        __builtin_amdgcn_sched_barrier(0);
        asm volatile("s_waitcnt vmcnt(0)" ::: "memory");   // A(63) done
        asm volatile("s_waitcnt lgkmcnt(0)" ::: "memory");
        __builtin_amdgcn_s_barrier();
    }
    // kt = 63: pure compute.
    compute(As0, Bs1);
#undef STEP_FULL

    // Epilogue: D layout col=lane&15, row=(lane>>4)*4+r; scale by 1/occ[t].
    #pragma unroll
    for (int fn = 0; fn < 4; ++fn) {
        const int t = n0 + wn * 64 + fn * 16 + l15;
        const float ro = 1.0f / fO[t];
        #pragma unroll
        for (int fm = 0; fm < 4; ++fm) {
            const int rb = wm * 64 + fm * 16 + kg * 4;
            #pragma unroll
            for (int r = 0; r < 4; ++r)
                fC[(size_t)(rb + r) * T_ + t] = acc[fm][fn][r] * ro;
        }
    }
}

extern "C" void kernel_launch(void* const* d_in, const int* in_sizes, int n_in,
                              void* d_out, int out_size, void* d_ws, size_t ws_size,
                              hipStream_t stream) {
    const float* features = (const float*)d_in[0];   // [16][256][2048] fp32
    const float* groups   = (const float*)d_in[1];   // [16][2048][4096] fp32
    const float* occur    = (const float*)d_in[2];   // [16][4096] fp32
    float* outp           = (float*)d_out;           // [16][256][4096] fp32

    // 128 KB dynamic LDS needs the opt-in attribute (host-side, capture-safe).
    hipFuncSetAttribute((const void*)mesh_unpool_gemm,
                        hipFuncAttributeMaxDynamicSharedMemorySize, 131072);
    mesh_unpool_gemm<<<dim3(256), dim3(1024, 1, 1), 131072, stream>>>(
        features, groups, occur, outp);
}